// Round 1
// baseline (312.308 us; speedup 1.0000x reference)
//
#include <hip/hip_runtime.h>

// TemplatePointwiseAttention on MI355X (gfx950) — round 6
// B=1, T=4, I=J=256 (P=65536 pixels), C_in=128, heads=4, att_c=64.
//
// Algebraic fusion (unchanged):
//   scores[t,p,h] = z[p] . M_h . a_t[p],   M_h = sum_{n%4==h} Wq[n](x)Wk[n] / sqrt(128)
//   out[p,m]      = sum_h Abar_h[p] . P_h[m] + bo[m],
//                   Abar_h[p] = sum_t softmax_w[t,p,h] * a_t[p]
//
// Round-6 restructure (latency-bound fix; old: 17.5% occ, 157KB LDS, scr fences):
//   * score: SWAPPED U GEMM  u^T = mfma(A=mcat_frag, B=z_frag)  puts u[k2][pixel]
//     with pixel = l15 in-lane -> score dot is in-lane f32 FMA + 2 shfl_xor.
//     No scratch LDS, no threadfence, no diag extraction.
//   * per-head LDS staging (32 KB) with XOR swizzle (unit ^= row&7): LDS
//     157KB->32KB, bank-balanced ds_read_b128 (8-cycle floor), 3-4 WG/CU.
//   * out: Abar accumulated in f32 straight from global f32 (no bf16->f32->bf16
//     double convert), packed once with v_cvt_pk_bf16_f32; per-head pcat staging.

#define PIX 65536

typedef __attribute__((ext_vector_type(8))) short s8v;      // bf16 x8 MFMA frag
typedef __attribute__((ext_vector_type(4))) float f4v;      // fp32 x4 acc
typedef __attribute__((ext_vector_type(4))) unsigned int u4v;
typedef __attribute__((ext_vector_type(4))) float fl4;

__device__ __forceinline__ unsigned short f2bf(float x) {
    unsigned int u = __float_as_uint(x);
    u = (u + 0x7FFFu + ((u >> 16) & 1u)) >> 16;   // round-to-nearest-even
    return (unsigned short)u;
}

// hw packed f32->bf16 (RNE); low16 = src0, high16 = src1
__device__ __forceinline__ unsigned int cvtpk(float lo, float hi) {
    unsigned int r;
    asm("v_cvt_pk_bf16_f32 %0, %1, %2" : "=v"(r) : "v"(lo), "v"(hi));
    return r;
}

__device__ __forceinline__ s8v pack8(fl4 d0, fl4 d1) {
    union { u4v u; s8v s; } cv;
    cv.u[0] = cvtpk(d0[0], d0[1]);
    cv.u[1] = cvtpk(d0[2], d0[3]);
    cv.u[2] = cvtpk(d1[0], d1[1]);
    cv.u[3] = cvtpk(d1[2], d1[3]);
    return cv.s;
}

__device__ __forceinline__ float bflo(unsigned int u) { return __uint_as_float(u << 16); }
__device__ __forceinline__ float bfhi(unsigned int u) { return __uint_as_float(u & 0xffff0000u); }

// Prologue: Mcat[n=h*128+k2][k1] = (1/sqrt128) sum_c Wq[c*4+h][k1] Wk[c*4+h][k2]
//           Pcat[m][kk=h*128+k]  = sum_c Wo[m][c*4+h] Wv[c*4+h][k]
__global__ __launch_bounds__(256) void build_weights(
        const float* __restrict__ Wq, const float* __restrict__ Wk,
        const float* __restrict__ Wv, const float* __restrict__ Wo,
        unsigned short* __restrict__ mcat, unsigned short* __restrict__ pcat) {
    int b = blockIdx.x;
    if (b < 256) {
        int idx = b * 256 + threadIdx.x;
        int n = idx >> 7, k1 = idx & 127;
        int h = n >> 7, k2 = n & 127;
        float s = 0.f;
        #pragma unroll 8
        for (int c = 0; c < 64; c++) {
            int r = c * 4 + h;
            s += Wq[r * 128 + k1] * Wk[r * 128 + k2];
        }
        mcat[idx] = f2bf(s * 0.088388347648318447f);
    } else {
        int idx = (b - 256) * 256 + threadIdx.x;
        int m = idx >> 9, kk = idx & 511;
        int h = kk >> 7, k = kk & 127;
        float s = 0.f;
        #pragma unroll 8
        for (int c = 0; c < 64; c++) {
            int r = c * 4 + h;
            s += Wo[m * 256 + r] * Wv[r * 128 + k];
        }
        pcat[idx] = f2bf(s);
    }
}

// ======================= Kernel S: scores + softmax =======================
// Grid 1024 x 256 threads (4 waves), 16 px per wave.
// LDS: one 32 KB head-slice of mcat, restaged per h, XOR-swizzled.
__global__ __launch_bounds__(256, 3) void score_kernel(
    const float* __restrict__ z2d, const float* __restrict__ t2d,
    const unsigned short* __restrict__ mcat, float* __restrict__ wbuf) {

    __shared__ unsigned short sm[128 * 128];        // 32 KB
    const int tid = threadIdx.x;
    const int wv = tid >> 6, lane = tid & 63, quad = lane >> 4, l15 = lane & 15;
    const int p = blockIdx.x * 64 + wv * 16 + l15;  // this lane's pixel

    // z fragments: B-operand of the swapped U GEMM (col=pixel=l15, k1=ks*32+quad*8+j)
    s8v za[4];
    {
        const float* zp = z2d + (size_t)p * 128 + quad * 8;
        #pragma unroll
        for (int ks = 0; ks < 4; ks++)
            za[ks] = pack8(*(const fl4*)(zp + ks * 32), *(const fl4*)(zp + ks * 32 + 4));
    }
    // a_t in C-layout pattern: lane (quad,l15) holds a_t[p][k2=cb*16+quad*4+{0..3}]
    // packed bf16 (2 u32 per (t,cb)); fl4 loads are 64B-coalesced across l15.
    unsigned int a2[4][8][2];
    #pragma unroll
    for (int t = 0; t < 4; t++) {
        const float* ap = t2d + ((size_t)t * PIX + p) * 128 + quad * 4;
        #pragma unroll
        for (int cb = 0; cb < 8; cb++) {
            const fl4 v = *(const fl4*)(ap + cb * 16);
            a2[t][cb][0] = cvtpk(v[0], v[1]);
            a2[t][cb][1] = cvtpk(v[2], v[3]);
        }
    }

    for (int h = 0; h < 4; h++) {
        __syncthreads();                            // prev head's reads done
        // stage mcat_h (128 rows x 128 k1 bf16 = 32 KB), XOR-swizzled 16B units
        #pragma unroll
        for (int i = 0; i < 8; i++) {
            const int g8 = i * 256 + tid;
            const int row = g8 >> 4, c8 = g8 & 15;
            *(u4v*)&sm[row * 128 + ((c8 ^ (row & 7)) * 8)] =
                *(const u4v*)(mcat + (size_t)(h * 128 + row) * 128 + c8 * 8);
        }
        __syncthreads();

        float ps[4] = {0.f, 0.f, 0.f, 0.f};
        #pragma unroll
        for (int cb = 0; cb < 8; cb++) {
            // u^T tile: C[row = k2 = cb*16+quad*4+r][col = pixel l15]
            f4v u = {0.f, 0.f, 0.f, 0.f};
            #pragma unroll
            for (int ks = 0; ks < 4; ks++) {
                const s8v a = *(const s8v*)&sm[(cb * 16 + l15) * 128 +
                                               (((ks * 4 + quad) ^ (l15 & 7)) * 8)];
                u = __builtin_amdgcn_mfma_f32_16x16x32_bf16(a, za[ks], u, 0, 0, 0);
            }
            // in-lane partial dot over the 4 k2 rows this lane holds
            #pragma unroll
            for (int t = 0; t < 4; t++) {
                const float a0 = bflo(a2[t][cb][0]), a1 = bfhi(a2[t][cb][0]);
                const float b0 = bflo(a2[t][cb][1]), b1 = bfhi(a2[t][cb][1]);
                ps[t] += u[0] * a0 + u[1] * a1 + u[2] * b0 + u[3] * b1;
            }
        }
        // reduce across the 4 quads (same l15) -> full score in every lane
        #pragma unroll
        for (int t = 0; t < 4; t++) {
            ps[t] += __shfl_xor(ps[t], 16);
            ps[t] += __shfl_xor(ps[t], 32);
        }
        const float mx = fmaxf(fmaxf(ps[0], ps[1]), fmaxf(ps[2], ps[3]));
        float e[4], sum = 0.f;
        #pragma unroll
        for (int t = 0; t < 4; t++) { e[t] = __expf(ps[t] - mx); sum += e[t]; }
        const float inv = 1.f / sum;
        if (quad == 0) {
            #pragma unroll
            for (int t = 0; t < 4; t++)
                wbuf[(size_t)(h * 4 + t) * PIX + p] = e[t] * inv;
        }
    }
}

// ======================= Kernel O: Abar + output GEMM =======================
// Grid 1024 x 256 threads (4 waves), 16 px per wave.
// LDS: one 32 KB head-slice of pcat, restaged per h, XOR-swizzled.
__global__ __launch_bounds__(256, 3) void out_kernel(
    const float* __restrict__ t2d, const unsigned short* __restrict__ pcat,
    const float* __restrict__ wbuf, const float* __restrict__ bo,
    float* __restrict__ out) {

    __shared__ unsigned short sm[128 * 128];        // 32 KB
    const int tid = threadIdx.x;
    const int wv = tid >> 6, lane = tid & 63, quad = lane >> 4, l15 = lane & 15;
    const int p0 = blockIdx.x * 64 + wv * 16;
    const int p = p0 + l15;

    float wgt[4][4];                                // [h][t]
    #pragma unroll
    for (int h = 0; h < 4; h++)
        #pragma unroll
        for (int t = 0; t < 4; t++)
            wgt[h][t] = wbuf[(size_t)(h * 4 + t) * PIX + p];

    // Abar A-frags: af[h][kf], pixel=l15 row, k = kf*32+quad*8+j.
    // f32 accumulate straight from global f32 -> single bf16 rounding.
    s8v af[4][4];
    #pragma unroll
    for (int kf = 0; kf < 4; kf++) {
        float f[4][8];
        #pragma unroll
        for (int h = 0; h < 4; h++)
            #pragma unroll
            for (int j = 0; j < 8; j++) f[h][j] = 0.f;
        #pragma unroll
        for (int t = 0; t < 4; t++) {
            const float* ap = t2d + ((size_t)t * PIX + p) * 128 + kf * 32 + quad * 8;
            const fl4 d0 = *(const fl4*)ap;
            const fl4 d1 = *(const fl4*)(ap + 4);
            #pragma unroll
            for (int h = 0; h < 4; h++) {
                const float w = wgt[h][t];
                #pragma unroll
                for (int j = 0; j < 4; j++) {
                    f[h][j]     += w * d0[j];
                    f[h][j + 4] += w * d1[j];
                }
            }
        }
        #pragma unroll
        for (int h = 0; h < 4; h++) {
            union { u4v u; s8v s; } cv;
            cv.u[0] = cvtpk(f[h][0], f[h][1]);
            cv.u[1] = cvtpk(f[h][2], f[h][3]);
            cv.u[2] = cvtpk(f[h][4], f[h][5]);
            cv.u[3] = cvtpk(f[h][6], f[h][7]);
            af[h][kf] = cv.s;
        }
    }

    f4v acc[8];
    #pragma unroll
    for (int ct = 0; ct < 8; ct++) acc[ct] = (f4v){0.f, 0.f, 0.f, 0.f};

    for (int h = 0; h < 4; h++) {
        __syncthreads();
        // stage pcat_h (128 m-rows x 128 k bf16 = 32 KB), XOR-swizzled
        #pragma unroll
        for (int i = 0; i < 8; i++) {
            const int g8 = i * 256 + tid;
            const int row = g8 >> 4, c8 = g8 & 15;
            *(u4v*)&sm[row * 128 + ((c8 ^ (row & 7)) * 8)] =
                *(const u4v*)(pcat + (size_t)row * 512 + h * 128 + c8 * 8);
        }
        __syncthreads();
        #pragma unroll
        for (int kf = 0; kf < 4; kf++)
            #pragma unroll
            for (int ct = 0; ct < 8; ct++) {
                const s8v b = *(const s8v*)&sm[(ct * 16 + l15) * 128 +
                                               (((kf * 4 + quad) ^ (l15 & 7)) * 8)];
                acc[ct] = __builtin_amdgcn_mfma_f32_16x16x32_bf16(af[h][kf], b, acc[ct], 0, 0, 0);
            }
    }

    // epilogue: bias + fp32 store (C row = pixel p0+quad*4+r, col = ct*16+l15)
    #pragma unroll
    for (int ct = 0; ct < 8; ct++) {
        const float bb = bo[ct * 16 + l15];
        #pragma unroll
        for (int r = 0; r < 4; r++)
            out[(size_t)(p0 + quad * 4 + r) * 128 + ct * 16 + l15] = acc[ct][r] + bb;
    }
}

extern "C" void kernel_launch(void* const* d_in, const int* in_sizes, int n_in,
                              void* d_out, int out_size, void* d_ws, size_t ws_size,
                              hipStream_t stream) {
    const float* z2d = (const float*)d_in[0];
    const float* t2d = (const float*)d_in[1];
    const float* Wq  = (const float*)d_in[2];
    const float* Wk  = (const float*)d_in[3];
    const float* Wv  = (const float*)d_in[4];
    const float* Wo  = (const float*)d_in[5];
    const float* bo  = (const float*)d_in[6];

    unsigned short* mcat = (unsigned short*)d_ws;          // 512*128 bf16 = 128 KB
    unsigned short* pcat = mcat + 512 * 128;               // 128*512 bf16 = 128 KB
    float* wbuf = (float*)(pcat + 128 * 512);              // 16*65536 fp32 = 4 MB

    build_weights<<<512, 256, 0, stream>>>(Wq, Wk, Wv, Wo, mcat, pcat);
    score_kernel<<<1024, 256, 0, stream>>>(z2d, t2d, mcat, wbuf);
    out_kernel<<<1024, 256, 0, stream>>>(t2d, pcat, wbuf, bo, (float*)d_out);
}